// Round 1
// 726.421 us; speedup vs baseline: 1.0108x; 1.0108x over previous
//
#include <hip/hip_runtime.h>
#include <hip/hip_bf16.h>

#define E_DIM 1024
#define HDIM  2730
#define HP    2752   // H padded to multiple of 64
#define NEXP  8
#define NTOK  4096
#define NPAIR 8192
#define NSLOT 72     // max m-tiles of 128 over all experts (<=71) + pad
#define LN_EPS 1e-5f

typedef __attribute__((ext_vector_type(8))) short  short8;
typedef __attribute__((ext_vector_type(4))) short  short4v;
typedef __attribute__((ext_vector_type(4))) float  floatx4;
typedef __attribute__((ext_vector_type(4))) int    intx4;

__device__ __forceinline__ __hip_bfloat16 f2bf(float f) { return __float2bfloat16(f); }

// async global->LDS, 16B per lane; LDS dest = wave-uniform base + lane*16
__device__ __forceinline__ void gload16(const __hip_bfloat16* g, __hip_bfloat16* l) {
  __builtin_amdgcn_global_load_lds(
      (const __attribute__((address_space(1))) void*)(g),
      (__attribute__((address_space(3))) void*)(l), 16, 0, 0);
}

// ---------------- router: fp32 logits, top-2, softmax weights ----------------
__global__ __launch_bounds__(256) void router_k(const float* __restrict__ x,
    const float* __restrict__ Wr, int* __restrict__ counts,
    int* __restrict__ tk_idx, float* __restrict__ tk_w) {
  int wid = threadIdx.x >> 6, lane = threadIdx.x & 63;
  int t = blockIdx.x * 4 + wid;
  const float* xr = x + (size_t)t * E_DIM;
  float xv[16];
#pragma unroll
  for (int i = 0; i < 16; ++i) xv[i] = xr[lane + 64 * i];
  float lg[8];
#pragma unroll
  for (int e = 0; e < 8; ++e) {
    const float* wr = Wr + e * E_DIM;
    float a = 0.f;
#pragma unroll
    for (int i = 0; i < 16; ++i) a += xv[i] * wr[lane + 64 * i];
#pragma unroll
    for (int o = 32; o; o >>= 1) a += __shfl_xor(a, o, 64);
    lg[e] = a;
  }
  if (lane == 0) {
    int i0 = 0; float l0 = lg[0];
#pragma unroll
    for (int e = 1; e < 8; ++e) if (lg[e] > l0) { l0 = lg[e]; i0 = e; }
    int i1 = -1; float l1 = -1e30f;
#pragma unroll
    for (int e = 0; e < 8; ++e) if (e != i0 && lg[e] > l1) { l1 = lg[e]; i1 = e; }
    float w0 = 1.f / (1.f + __expf(l1 - l0));
    atomicAdd(&counts[i0], 1);
    atomicAdd(&counts[i1], 1);
    tk_idx[2 * t]     = i0;  tk_idx[2 * t + 1] = i1;
    tk_w[2 * t]       = w0;  tk_w[2 * t + 1]   = 1.f - w0;
  }
}

// offsets + compact (expert, m0) tile table: active slots contiguous from 0.
__global__ void offsets_k(const int* __restrict__ counts, int* __restrict__ offsets,
                          int* __restrict__ cursor,
                          int* __restrict__ slot_e, int* __restrict__ slot_m0) {
  if (threadIdx.x == 0) {
    int off = 0, s = 0;
    for (int e = 0; e < NEXP; ++e) {
      offsets[e] = off; cursor[e] = off;
      for (int m0 = 0; m0 < counts[e]; m0 += 128) { slot_e[s] = e; slot_m0[s] = m0; ++s; }
      off += counts[e];
    }
    for (; s < NSLOT; ++s) { slot_e[s] = -1; slot_m0[s] = 0; }
  }
}

__global__ __launch_bounds__(256) void scatter_k(const int* __restrict__ tk_idx,
    const float* __restrict__ tk_w, int* __restrict__ cursor,
    int* __restrict__ pair_token, float* __restrict__ pair_w, int* __restrict__ pair_pos) {
  int t = blockIdx.x * 256 + threadIdx.x;
#pragma unroll
  for (int k = 0; k < 2; ++k) {
    int e = tk_idx[2 * t + k];
    int pos = atomicAdd(&cursor[e], 1);
    pair_token[pos] = t;
    pair_w[pos] = tk_w[2 * t + k];
    pair_pos[2 * t + k] = pos;
  }
}

// ---------------- expert-sorted token rows: xs[p] = bf16(x[pair_token[p]]) ----------------
__global__ __launch_bounds__(256) void gatherx_k(const float* __restrict__ x,
    const int* __restrict__ pair_token, __hip_bfloat16* __restrict__ xs) {
  int p = blockIdx.x;
  int t = pair_token[p];
  const float* src = x + (size_t)t * E_DIM;
  __hip_bfloat16* dst = xs + (size_t)p * E_DIM;
  int i = threadIdx.x * 4;
  floatx4 v = *(const floatx4*)(src + i);
  union { __hip_bfloat16 h[4]; short4v s; } u;
#pragma unroll
  for (int j = 0; j < 4; ++j) u.h[j] = f2bf(v[j]);
  *(short4v*)(dst + i) = u.s;
}

// ------------- transpose + convert: in fp32 [R][C] -> out bf16 [Cp][outRS] -------------
__global__ __launch_bounds__(256) void tcvt_k(const float* __restrict__ in,
    __hip_bfloat16* __restrict__ out, int R, int C, int outRS,
    size_t inExpStride, size_t outExpStride) {
  __shared__ float tile[64 * 65];
  int e = blockIdx.z;
  const float* ip = in + inExpStride * e;
  __hip_bfloat16* op = out + outExpStride * e;
  int c0 = blockIdx.x * 64, r0 = blockIdx.y * 64;
#pragma unroll
  for (int i = 0; i < 16; ++i) {
    int idx = i * 256 + threadIdx.x;
    int rr = idx >> 6, cc = idx & 63;
    int gr = r0 + rr, gc = c0 + cc;
    tile[rr * 65 + cc] = (gr < R && gc < C) ? ip[(size_t)gr * C + gc] : 0.f;
  }
  __syncthreads();
#pragma unroll
  for (int i = 0; i < 2; ++i) {
    int idx = i * 256 + threadIdx.x;
    int cc = idx >> 3, rb = (idx & 7) * 8;
    union { __hip_bfloat16 h[8]; intx4 v; } u;
#pragma unroll
    for (int j = 0; j < 8; ++j) u.h[j] = f2bf(tile[(rb + j) * 65 + cc]);
    *(intx4*)(op + (size_t)(c0 + cc) * outRS + (r0 + rb)) = u.v;
  }
}

// ---------------- GEMM1: h = silu(xs@Wv+bv) * (xs@Wg+bg) ----------------
// 128m x 64n block, BK=64. global_load_lds staging, linear LDS with XOR-16B-chunk
// swizzle (pre-swizzled global source + swizzled ds_read, rule #21).
__global__ __launch_bounds__(256) void gemm1_k(
    const __hip_bfloat16* __restrict__ xs,
    const int* __restrict__ counts, const int* __restrict__ offsets,
    const int* __restrict__ slot_e, const int* __restrict__ slot_m0,
    const float* __restrict__ bv, const float* __restrict__ bg,
    const __hip_bfloat16* __restrict__ WvT, const __hip_bfloat16* __restrict__ WgT,
    __hip_bfloat16* __restrict__ h) {
  int slot = blockIdx.y;
  int e = slot_e[slot];
  if (e < 0) return;
  int m0 = slot_m0[slot];
  int Me = counts[e], off = offsets[e];
  int n0 = blockIdx.x * 64;

  __shared__ __align__(16) __hip_bfloat16 sA[128 * 64];
  __shared__ __align__(16) __hip_bfloat16 sBv[64 * 64];
  __shared__ __align__(16) __hip_bfloat16 sBg[64 * 64];

  int tid = threadIdx.x;
  int wid = tid >> 6, lane = tid & 63;
  int wm = wid >> 1, wn = wid & 1;
  int q = lane >> 4, r = lane & 15;
  int key = r & 7;

  // fragment read offsets (in halfs); chunk = (s*4+q) ^ (row&7), row&7 == r&7
  int aoff[4][2], boff[2][2];
#pragma unroll
  for (int mi = 0; mi < 4; ++mi)
#pragma unroll
    for (int s = 0; s < 2; ++s)
      aoff[mi][s] = (wm * 64 + mi * 16 + r) * 64 + ((((s << 2) + q) ^ key) << 3);
#pragma unroll
  for (int ni = 0; ni < 2; ++ni)
#pragma unroll
    for (int s = 0; s < 2; ++s)
      boff[ni][s] = (wn * 32 + ni * 16 + r) * 64 + ((((s << 2) + q) ^ key) << 3);

  // staging: each instr moves 1KB/wave = 8 rows x 128B. Lane l covers
  // LDS (row = c*8 + l>>3, chunk = l&7); source chunk = (l&7) ^ (l>>3).
  int srow8  = lane >> 3;
  int schunk = (lane & 7) ^ srow8;
  const __hip_bfloat16* gA[4];
  __hip_bfloat16* lA[4];
#pragma unroll
  for (int i = 0; i < 4; ++i) {
    int c = i * 4 + wid;
    gA[i] = xs + (size_t)(off + m0 + c * 8 + srow8) * E_DIM + schunk * 8;
    lA[i] = sA + c * 512;
  }
  const __hip_bfloat16* gBvp[2];
  const __hip_bfloat16* gBgp[2];
  __hip_bfloat16* lBv[2];
  __hip_bfloat16* lBg[2];
  size_t wb = (size_t)e * ((size_t)HP * E_DIM);
#pragma unroll
  for (int i = 0; i < 2; ++i) {
    int c = i * 4 + wid;
    size_t rowoff = wb + (size_t)(n0 + c * 8 + srow8) * E_DIM + schunk * 8;
    gBvp[i] = WvT + rowoff;
    gBgp[i] = WgT + rowoff;
    lBv[i] = sBv + c * 512;
    lBg[i] = sBg + c * 512;
  }

  floatx4 accv[4][2], accg[4][2];
  floatx4 zz = {0.f, 0.f, 0.f, 0.f};
#pragma unroll
  for (int mi = 0; mi < 4; ++mi)
#pragma unroll
    for (int ni = 0; ni < 2; ++ni) { accv[mi][ni] = zz; accg[mi][ni] = zz; }

  for (int kt = 0; kt < E_DIM / 64; ++kt) {
    int ko = kt * 64;
#pragma unroll
    for (int i = 0; i < 4; ++i) gload16(gA[i] + ko, lA[i]);
#pragma unroll
    for (int i = 0; i < 2; ++i) {
      gload16(gBvp[i] + ko, lBv[i]);
      gload16(gBgp[i] + ko, lBg[i]);
    }
    __syncthreads();
#pragma unroll
    for (int s = 0; s < 2; ++s) {
      short8 av[4];
#pragma unroll
      for (int mi = 0; mi < 4; ++mi)
        av[mi] = *(const short8*)(sA + aoff[mi][s]);
#pragma unroll
      for (int ni = 0; ni < 2; ++ni) {
        short8 b8v = *(const short8*)(sBv + boff[ni][s]);
        short8 b8g = *(const short8*)(sBg + boff[ni][s]);
#pragma unroll
        for (int mi = 0; mi < 4; ++mi) {
          accv[mi][ni] = __builtin_amdgcn_mfma_f32_16x16x32_bf16(av[mi], b8v, accv[mi][ni], 0, 0, 0);
          accg[mi][ni] = __builtin_amdgcn_mfma_f32_16x16x32_bf16(av[mi], b8g, accg[mi][ni], 0, 0, 0);
        }
      }
    }
    __syncthreads();
  }

#pragma unroll
  for (int mi = 0; mi < 4; ++mi) {
#pragma unroll
    for (int rr = 0; rr < 4; ++rr) {
      int m_loc = wm * 64 + mi * 16 + q * 4 + rr;
      int m = m0 + m_loc;
      if (m >= Me) continue;
      size_t hrow = (size_t)(off + m) * HP;
#pragma unroll
      for (int ni = 0; ni < 2; ++ni) {
        int n = n0 + wn * 32 + ni * 16 + r;
        float bvv = (n < HDIM) ? bv[e * HDIM + n] : 0.f;
        float bgv = (n < HDIM) ? bg[e * HDIM + n] : 0.f;
        float hv = accv[mi][ni][rr] + bvv;
        float hg = accg[mi][ni][rr] + bgv;
        float sgm = 1.f / (1.f + __expf(-hv));
        h[hrow + n] = f2bf(hv * sgm * hg);
      }
    }
  }
}

// ---------------- GEMM2: pair_out = h @ Wo + bo ----------------
__global__ __launch_bounds__(256) void gemm2_k(
    const __hip_bfloat16* __restrict__ hb,
    const int* __restrict__ counts, const int* __restrict__ offsets,
    const int* __restrict__ slot_e, const int* __restrict__ slot_m0,
    const float* __restrict__ bo,
    const __hip_bfloat16* __restrict__ WoT,
    float* __restrict__ pout) {
  int slot = blockIdx.y;
  int e = slot_e[slot];
  if (e < 0) return;
  int m0 = slot_m0[slot];
  int Me = counts[e], off = offsets[e];
  int n0 = blockIdx.x * 64;

  __shared__ __align__(16) __hip_bfloat16 sA[128 * 64];
  __shared__ __align__(16) __hip_bfloat16 sB[64 * 64];

  int tid = threadIdx.x;
  int wid = tid >> 6, lane = tid & 63;
  int wm = wid >> 1, wn = wid & 1;
  int q = lane >> 4, r = lane & 15;
  int key = r & 7;

  int aoff[4][2], boff[2][2];
#pragma unroll
  for (int mi = 0; mi < 4; ++mi)
#pragma unroll
    for (int s = 0; s < 2; ++s)
      aoff[mi][s] = (wm * 64 + mi * 16 + r) * 64 + ((((s << 2) + q) ^ key) << 3);
#pragma unroll
  for (int ni = 0; ni < 2; ++ni)
#pragma unroll
    for (int s = 0; s < 2; ++s)
      boff[ni][s] = (wn * 32 + ni * 16 + r) * 64 + ((((s << 2) + q) ^ key) << 3);

  int srow8  = lane >> 3;
  int schunk = (lane & 7) ^ srow8;
  const __hip_bfloat16* gA[4];
  __hip_bfloat16* lA[4];
#pragma unroll
  for (int i = 0; i < 4; ++i) {
    int c = i * 4 + wid;
    gA[i] = hb + (size_t)(off + m0 + c * 8 + srow8) * HP + schunk * 8;
    lA[i] = sA + c * 512;
  }
  const __hip_bfloat16* gB[2];
  __hip_bfloat16* lB[2];
#pragma unroll
  for (int i = 0; i < 2; ++i) {
    int c = i * 4 + wid;
    gB[i] = WoT + (size_t)e * ((size_t)E_DIM * HP) +
            (size_t)(n0 + c * 8 + srow8) * HP + schunk * 8;
    lB[i] = sB + c * 512;
  }

  floatx4 acc[4][2];
  floatx4 zz = {0.f, 0.f, 0.f, 0.f};
#pragma unroll
  for (int mi = 0; mi < 4; ++mi)
#pragma unroll
    for (int ni = 0; ni < 2; ++ni) acc[mi][ni] = zz;

  for (int kt = 0; kt < HP / 64; ++kt) {
    int ko = kt * 64;
#pragma unroll
    for (int i = 0; i < 4; ++i) gload16(gA[i] + ko, lA[i]);
#pragma unroll
    for (int i = 0; i < 2; ++i) gload16(gB[i] + ko, lB[i]);
    __syncthreads();
#pragma unroll
    for (int s = 0; s < 2; ++s) {
      short8 av[4];
#pragma unroll
      for (int mi = 0; mi < 4; ++mi)
        av[mi] = *(const short8*)(sA + aoff[mi][s]);
#pragma unroll
      for (int ni = 0; ni < 2; ++ni) {
        short8 b8 = *(const short8*)(sB + boff[ni][s]);
#pragma unroll
        for (int mi = 0; mi < 4; ++mi)
          acc[mi][ni] = __builtin_amdgcn_mfma_f32_16x16x32_bf16(av[mi], b8, acc[mi][ni], 0, 0, 0);
      }
    }
    __syncthreads();
  }

#pragma unroll
  for (int mi = 0; mi < 4; ++mi) {
#pragma unroll
    for (int rr = 0; rr < 4; ++rr) {
      int m_loc = wm * 64 + mi * 16 + q * 4 + rr;
      int m = m0 + m_loc;
      if (m >= Me) continue;
      size_t orow = (size_t)(off + m) * E_DIM;
#pragma unroll
      for (int ni = 0; ni < 2; ++ni) {
        int n = n0 + wn * 32 + ni * 16 + r;
        pout[orow + n] = acc[mi][ni][rr] + bo[e * E_DIM + n];
      }
    }
  }
}

// ---------------- combine + residual + LayerNorm ----------------
__global__ __launch_bounds__(256) void ln_k(const float* __restrict__ x,
    const float* __restrict__ pout, const int* __restrict__ pair_pos,
    const float* __restrict__ pair_w, const float* __restrict__ ln_g,
    const float* __restrict__ ln_b, float* __restrict__ out) {
  int t = blockIdx.x, tid = threadIdx.x;
  int p0 = pair_pos[2 * t], p1 = pair_pos[2 * t + 1];
  float w0 = pair_w[p0], w1 = pair_w[p1];
  const float* xr = x + (size_t)t * E_DIM;
  const float* r0 = pout + (size_t)p0 * E_DIM;
  const float* r1 = pout + (size_t)p1 * E_DIM;
  float y[4];
  float s = 0.f, ss = 0.f;
#pragma unroll
  for (int i = 0; i < 4; ++i) {
    int e = tid + 256 * i;
    y[i] = xr[e] + w0 * r0[e] + w1 * r1[e];
    s += y[i];
    ss += y[i] * y[i];
  }
#pragma unroll
  for (int o = 32; o; o >>= 1) { s += __shfl_xor(s, o, 64); ss += __shfl_xor(ss, o, 64); }
  __shared__ float red[8];
  int wid = tid >> 6, lane = tid & 63;
  if (lane == 0) { red[wid] = s; red[4 + wid] = ss; }
  __syncthreads();
  s  = red[0] + red[1] + red[2] + red[3];
  ss = red[4] + red[5] + red[6] + red[7];
  float mu = s * (1.f / E_DIM);
  float var = ss * (1.f / E_DIM) - mu * mu;
  float rs = rsqrtf(var + LN_EPS);
#pragma unroll
  for (int i = 0; i < 4; ++i) {
    int e = tid + 256 * i;
    out[(size_t)t * E_DIM + e] = ln_g[e] * (y[i] - mu) * rs + ln_b[e];
  }
}

extern "C" void kernel_launch(void* const* d_in, const int* in_sizes, int n_in,
                              void* d_out, int out_size, void* d_ws, size_t ws_size,
                              hipStream_t stream) {
  const float* x    = (const float*)d_in[0];
  const float* Wr   = (const float*)d_in[1];
  const float* Wv   = (const float*)d_in[2];
  const float* bv   = (const float*)d_in[3];
  const float* Wg   = (const float*)d_in[4];
  const float* bg   = (const float*)d_in[5];
  const float* Wo   = (const float*)d_in[6];
  const float* bo   = (const float*)d_in[7];
  const float* ln_g = (const float*)d_in[8];
  const float* ln_b = (const float*)d_in[9];
  float* out = (float*)d_out;

  char* ws = (char*)d_ws;
  size_t off = 0;
  auto alloc = [&](size_t bytes) -> void* {
    void* p = ws + off;
    off = (off + bytes + 255) & ~(size_t)255;
    return p;
  };
  int*   counts     = (int*)alloc(32);
  int*   cursor     = (int*)alloc(32);
  int*   offsets    = (int*)alloc(32);
  int*   slot_e     = (int*)alloc(NSLOT * 4);
  int*   slot_m0    = (int*)alloc(NSLOT * 4);
  int*   tk_idx     = (int*)alloc((size_t)NTOK * 2 * 4);
  float* tk_w       = (float*)alloc((size_t)NTOK * 2 * 4);
  int*   pair_token = (int*)alloc((size_t)NPAIR * 4);
  float* pair_w     = (float*)alloc((size_t)NPAIR * 4);
  int*   pair_pos   = (int*)alloc((size_t)NPAIR * 4);
  __hip_bfloat16* xs   = (__hip_bfloat16*)alloc((size_t)(NPAIR + 128) * E_DIM * 2);
  __hip_bfloat16* hbuf = (__hip_bfloat16*)alloc((size_t)(NPAIR + 128) * HP * 2);
  float* pout = (float*)alloc((size_t)NPAIR * E_DIM * 4);

  size_t welems = (size_t)NEXP * HP * E_DIM;
  __hip_bfloat16* WvT = (__hip_bfloat16*)alloc(welems * 2);
  __hip_bfloat16* WgT = (__hip_bfloat16*)alloc(welems * 2);
  __hip_bfloat16* WoT = (__hip_bfloat16*)alloc(welems * 2);

  hipMemsetAsync(d_ws, 0, 1024, stream);  // counts / cursor / offsets / slots

  router_k<<<NTOK / 4, 256, 0, stream>>>(x, Wr, counts, tk_idx, tk_w);
  offsets_k<<<1, 64, 0, stream>>>(counts, offsets, cursor, slot_e, slot_m0);
  scatter_k<<<NTOK / 256, 256, 0, stream>>>(tk_idx, tk_w, cursor, pair_token, pair_w, pair_pos);
  gatherx_k<<<NPAIR, 256, 0, stream>>>(x, pair_token, xs);

  tcvt_k<<<dim3(HP / 64, E_DIM / 64, NEXP), 256, 0, stream>>>(
      Wv, WvT, E_DIM, HDIM, E_DIM, (size_t)E_DIM * HDIM, (size_t)HP * E_DIM);
  tcvt_k<<<dim3(HP / 64, E_DIM / 64, NEXP), 256, 0, stream>>>(
      Wg, WgT, E_DIM, HDIM, E_DIM, (size_t)E_DIM * HDIM, (size_t)HP * E_DIM);
  tcvt_k<<<dim3(E_DIM / 64, HP / 64, NEXP), 256, 0, stream>>>(
      Wo, WoT, HDIM, E_DIM, HP, (size_t)HDIM * E_DIM, (size_t)E_DIM * HP);

  gemm1_k<<<dim3(HP / 64, NSLOT), 256, 0, stream>>>(
      xs, counts, offsets, slot_e, slot_m0, bv, bg, WvT, WgT, hbuf);
  gemm2_k<<<dim3(E_DIM / 64, NSLOT), 256, 0, stream>>>(
      hbuf, counts, offsets, slot_e, slot_m0, bo, WoT, pout);

  ln_k<<<NTOK, 256, 0, stream>>>(x, pout, pair_pos, pair_w, ln_g, ln_b, out);
}

// Round 2
// 674.061 us; speedup vs baseline: 1.0894x; 1.0777x over previous
//
#include <hip/hip_runtime.h>
#include <hip/hip_bf16.h>

#define E_DIM 1024
#define HDIM  2730
#define HP    2816   // H padded to multiple of 128
#define NEXP  8
#define NTOK  4096
#define NPAIR 8192
#define NSLOT 72     // max m-tiles of 128 over all experts (<=71) + pad
#define LN_EPS 1e-5f

typedef __attribute__((ext_vector_type(8))) short  short8;
typedef __attribute__((ext_vector_type(4))) short  short4v;
typedef __attribute__((ext_vector_type(4))) float  floatx4;
typedef __attribute__((ext_vector_type(4))) int    intx4;

__device__ __forceinline__ __hip_bfloat16 f2bf(float f) { return __float2bfloat16(f); }

// async global->LDS, 16B per lane; LDS dest = wave-uniform base + lane*16
__device__ __forceinline__ void gload16(const __hip_bfloat16* g, __hip_bfloat16* l) {
  __builtin_amdgcn_global_load_lds(
      (const __attribute__((address_space(1))) void*)(g),
      (__attribute__((address_space(3))) void*)(l), 16, 0, 0);
}

// ---------------- router: fp32 logits, top-2, softmax weights ----------------
__global__ __launch_bounds__(256) void router_k(const float* __restrict__ x,
    const float* __restrict__ Wr, int* __restrict__ counts,
    int* __restrict__ tk_idx, float* __restrict__ tk_w) {
  int wid = threadIdx.x >> 6, lane = threadIdx.x & 63;
  int t = blockIdx.x * 4 + wid;
  const float* xr = x + (size_t)t * E_DIM;
  float xv[16];
#pragma unroll
  for (int i = 0; i < 16; ++i) xv[i] = xr[lane + 64 * i];
  float lg[8];
#pragma unroll
  for (int e = 0; e < 8; ++e) {
    const float* wr = Wr + e * E_DIM;
    float a = 0.f;
#pragma unroll
    for (int i = 0; i < 16; ++i) a += xv[i] * wr[lane + 64 * i];
#pragma unroll
    for (int o = 32; o; o >>= 1) a += __shfl_xor(a, o, 64);
    lg[e] = a;
  }
  if (lane == 0) {
    int i0 = 0; float l0 = lg[0];
#pragma unroll
    for (int e = 1; e < 8; ++e) if (lg[e] > l0) { l0 = lg[e]; i0 = e; }
    int i1 = -1; float l1 = -1e30f;
#pragma unroll
    for (int e = 0; e < 8; ++e) if (e != i0 && lg[e] > l1) { l1 = lg[e]; i1 = e; }
    float w0 = 1.f / (1.f + __expf(l1 - l0));
    atomicAdd(&counts[i0], 1);
    atomicAdd(&counts[i1], 1);
    tk_idx[2 * t]     = i0;  tk_idx[2 * t + 1] = i1;
    tk_w[2 * t]       = w0;  tk_w[2 * t + 1]   = 1.f - w0;
  }
}

// offsets + compact (expert, m0) tile table: active slots contiguous from 0.
__global__ void offsets_k(const int* __restrict__ counts, int* __restrict__ offsets,
                          int* __restrict__ cursor,
                          int* __restrict__ slot_e, int* __restrict__ slot_m0) {
  if (threadIdx.x == 0) {
    int off = 0, s = 0;
    for (int e = 0; e < NEXP; ++e) {
      offsets[e] = off; cursor[e] = off;
      for (int m0 = 0; m0 < counts[e]; m0 += 128) { slot_e[s] = e; slot_m0[s] = m0; ++s; }
      off += counts[e];
    }
    for (; s < NSLOT; ++s) { slot_e[s] = -1; slot_m0[s] = 0; }
  }
}

__global__ __launch_bounds__(256) void scatter_k(const int* __restrict__ tk_idx,
    const float* __restrict__ tk_w, int* __restrict__ cursor,
    int* __restrict__ pair_token, float* __restrict__ pair_w, int* __restrict__ pair_pos) {
  int t = blockIdx.x * 256 + threadIdx.x;
#pragma unroll
  for (int k = 0; k < 2; ++k) {
    int e = tk_idx[2 * t + k];
    int pos = atomicAdd(&cursor[e], 1);
    pair_token[pos] = t;
    pair_w[pos] = tk_w[2 * t + k];
    pair_pos[2 * t + k] = pos;
  }
}

// ---------------- expert-sorted token rows: xs[p] = bf16(x[pair_token[p]]) ----------------
__global__ __launch_bounds__(256) void gatherx_k(const float* __restrict__ x,
    const int* __restrict__ pair_token, __hip_bfloat16* __restrict__ xs) {
  int p = blockIdx.x;
  int t = pair_token[p];
  const float* src = x + (size_t)t * E_DIM;
  __hip_bfloat16* dst = xs + (size_t)p * E_DIM;
  int i = threadIdx.x * 4;
  floatx4 v = *(const floatx4*)(src + i);
  union { __hip_bfloat16 h[4]; short4v s; } u;
#pragma unroll
  for (int j = 0; j < 4; ++j) u.h[j] = f2bf(v[j]);
  *(short4v*)(dst + i) = u.s;
}

// ------------- transpose + convert: in fp32 [R][C] -> out bf16 [Cp][outRS] -------------
__global__ __launch_bounds__(256) void tcvt_k(const float* __restrict__ in,
    __hip_bfloat16* __restrict__ out, int R, int C, int outRS,
    size_t inExpStride, size_t outExpStride) {
  __shared__ float tile[64 * 65];
  int e = blockIdx.z;
  const float* ip = in + inExpStride * e;
  __hip_bfloat16* op = out + outExpStride * e;
  int c0 = blockIdx.x * 64, r0 = blockIdx.y * 64;
#pragma unroll
  for (int i = 0; i < 16; ++i) {
    int idx = i * 256 + threadIdx.x;
    int rr = idx >> 6, cc = idx & 63;
    int gr = r0 + rr, gc = c0 + cc;
    tile[rr * 65 + cc] = (gr < R && gc < C) ? ip[(size_t)gr * C + gc] : 0.f;
  }
  __syncthreads();
#pragma unroll
  for (int i = 0; i < 2; ++i) {
    int idx = i * 256 + threadIdx.x;
    int cc = idx >> 3, rb = (idx & 7) * 8;
    union { __hip_bfloat16 h[8]; intx4 v; } u;
#pragma unroll
    for (int j = 0; j < 8; ++j) u.h[j] = f2bf(tile[(rb + j) * 65 + cc]);
    *(intx4*)(op + (size_t)(c0 + cc) * outRS + (r0 + rb)) = u.v;
  }
}

// ---------------- GEMM1: h = silu(xs@Wv+bv) * (xs@Wg+bg) ----------------
// 128m x 128n block (dual B), BK=64. global_load_lds staging, linear LDS with
// XOR-16B-chunk swizzle (pre-swizzled global source + swizzled ds_read).
__global__ __launch_bounds__(256, 2) void gemm1_k(
    const __hip_bfloat16* __restrict__ xs,
    const int* __restrict__ counts, const int* __restrict__ offsets,
    const int* __restrict__ slot_e, const int* __restrict__ slot_m0,
    const float* __restrict__ bv, const float* __restrict__ bg,
    const __hip_bfloat16* __restrict__ WvT, const __hip_bfloat16* __restrict__ WgT,
    __hip_bfloat16* __restrict__ h) {
  int slot = blockIdx.y;
  int e = slot_e[slot];
  if (e < 0) return;
  int m0 = slot_m0[slot];
  int Me = counts[e], off = offsets[e];
  int n0 = blockIdx.x * 128;

  __shared__ __align__(16) __hip_bfloat16 sA[128 * 64];
  __shared__ __align__(16) __hip_bfloat16 sBv[128 * 64];
  __shared__ __align__(16) __hip_bfloat16 sBg[128 * 64];

  int tid = threadIdx.x;
  int wid = tid >> 6, lane = tid & 63;
  int wm = wid >> 1, wn = wid & 1;
  int q = lane >> 4, r = lane & 15;
  int key = r & 7;

  // fragment read offsets (in halfs); chunk = (s*4+q) ^ (row&7), row&7 == r&7
  int sw[2];
  sw[0] = ((q ^ key) << 3);
  sw[1] = (((4 + q) ^ key) << 3);
  int arow = (wm * 64 + r) * 64;
  int brow = (wn * 64 + r) * 64;

  // staging: each gload16 moves 1KB/wave = 8 rows x 128B. Lane l covers
  // LDS (row = c*8 + l>>3, chunk = l&7); source chunk = (l&7) ^ (l>>3).
  int srow8  = lane >> 3;
  int schunk = (lane & 7) ^ srow8;
  const __hip_bfloat16* gA0 = xs + (size_t)(off + m0 + wid * 8 + srow8) * E_DIM + schunk * 8;
  size_t wb = (size_t)e * ((size_t)HP * E_DIM);
  size_t browoff = wb + (size_t)(n0 + wid * 8 + srow8) * E_DIM + schunk * 8;
  const __hip_bfloat16* gBv0 = WvT + browoff;
  const __hip_bfloat16* gBg0 = WgT + browoff;
  __hip_bfloat16* lA0  = sA  + wid * 512;
  __hip_bfloat16* lBv0 = sBv + wid * 512;
  __hip_bfloat16* lBg0 = sBg + wid * 512;

  floatx4 accv[4][4], accg[4][4];
  floatx4 zz = {0.f, 0.f, 0.f, 0.f};
#pragma unroll
  for (int mi = 0; mi < 4; ++mi)
#pragma unroll
    for (int ni = 0; ni < 4; ++ni) { accv[mi][ni] = zz; accg[mi][ni] = zz; }

  for (int kt = 0; kt < E_DIM / 64; ++kt) {
    int ko = kt * 64;
#pragma unroll
    for (int i = 0; i < 4; ++i) gload16(gA0  + ko + (size_t)i * 32 * E_DIM, lA0  + i * 2048);
#pragma unroll
    for (int i = 0; i < 4; ++i) gload16(gBv0 + ko + (size_t)i * 32 * E_DIM, lBv0 + i * 2048);
#pragma unroll
    for (int i = 0; i < 4; ++i) gload16(gBg0 + ko + (size_t)i * 32 * E_DIM, lBg0 + i * 2048);
    __syncthreads();
#pragma unroll
    for (int s = 0; s < 2; ++s) {
      short8 av[4];
#pragma unroll
      for (int mi = 0; mi < 4; ++mi)
        av[mi] = *(const short8*)(sA + arow + mi * 16 * 64 + sw[s]);
#pragma unroll
      for (int ni = 0; ni < 4; ++ni) {
        short8 b8v = *(const short8*)(sBv + brow + ni * 16 * 64 + sw[s]);
        short8 b8g = *(const short8*)(sBg + brow + ni * 16 * 64 + sw[s]);
#pragma unroll
        for (int mi = 0; mi < 4; ++mi) {
          accv[mi][ni] = __builtin_amdgcn_mfma_f32_16x16x32_bf16(av[mi], b8v, accv[mi][ni], 0, 0, 0);
          accg[mi][ni] = __builtin_amdgcn_mfma_f32_16x16x32_bf16(av[mi], b8g, accg[mi][ni], 0, 0, 0);
        }
      }
    }
    __syncthreads();
  }

  // epilogue: silu(hv) * hg -> h (bf16)
  float bvv[4], bgv[4];
#pragma unroll
  for (int ni = 0; ni < 4; ++ni) {
    int n = n0 + wn * 64 + ni * 16 + r;
    bvv[ni] = (n < HDIM) ? bv[e * HDIM + n] : 0.f;
    bgv[ni] = (n < HDIM) ? bg[e * HDIM + n] : 0.f;
  }
#pragma unroll
  for (int mi = 0; mi < 4; ++mi) {
#pragma unroll
    for (int rr = 0; rr < 4; ++rr) {
      int m_loc = wm * 64 + mi * 16 + q * 4 + rr;
      int m = m0 + m_loc;
      if (m >= Me) continue;
      size_t hrow = (size_t)(off + m) * HP;
#pragma unroll
      for (int ni = 0; ni < 4; ++ni) {
        int n = n0 + wn * 64 + ni * 16 + r;
        float hv = accv[mi][ni][rr] + bvv[ni];
        float hg = accg[mi][ni][rr] + bgv[ni];
        float sgm = 1.f / (1.f + __expf(-hv));
        h[hrow + n] = f2bf(hv * sgm * hg);
      }
    }
  }
}

// ---------------- GEMM2: pair_out = h @ Wo + bo ----------------
// 128m x 128n block, BK=64, same staging/swizzle scheme.
__global__ __launch_bounds__(256) void gemm2_k(
    const __hip_bfloat16* __restrict__ hb,
    const int* __restrict__ counts, const int* __restrict__ offsets,
    const int* __restrict__ slot_e, const int* __restrict__ slot_m0,
    const float* __restrict__ bo,
    const __hip_bfloat16* __restrict__ WoT,
    float* __restrict__ pout) {
  int slot = blockIdx.y;
  int e = slot_e[slot];
  if (e < 0) return;
  int m0 = slot_m0[slot];
  int Me = counts[e], off = offsets[e];
  int n0 = blockIdx.x * 128;

  __shared__ __align__(16) __hip_bfloat16 sA[128 * 64];
  __shared__ __align__(16) __hip_bfloat16 sB[128 * 64];

  int tid = threadIdx.x;
  int wid = tid >> 6, lane = tid & 63;
  int wm = wid >> 1, wn = wid & 1;
  int q = lane >> 4, r = lane & 15;
  int key = r & 7;

  int sw[2];
  sw[0] = ((q ^ key) << 3);
  sw[1] = (((4 + q) ^ key) << 3);
  int arow = (wm * 64 + r) * 64;
  int brow = (wn * 64 + r) * 64;

  int srow8  = lane >> 3;
  int schunk = (lane & 7) ^ srow8;
  const __hip_bfloat16* gA0 = hb + (size_t)(off + m0 + wid * 8 + srow8) * HP + schunk * 8;
  const __hip_bfloat16* gB0 = WoT + (size_t)e * ((size_t)E_DIM * HP) +
                              (size_t)(n0 + wid * 8 + srow8) * HP + schunk * 8;
  __hip_bfloat16* lA0 = sA + wid * 512;
  __hip_bfloat16* lB0 = sB + wid * 512;

  floatx4 acc[4][4];
  floatx4 zz = {0.f, 0.f, 0.f, 0.f};
#pragma unroll
  for (int mi = 0; mi < 4; ++mi)
#pragma unroll
    for (int ni = 0; ni < 4; ++ni) acc[mi][ni] = zz;

  for (int kt = 0; kt < HP / 64; ++kt) {
    int ko = kt * 64;
#pragma unroll
    for (int i = 0; i < 4; ++i) gload16(gA0 + ko + (size_t)i * 32 * HP, lA0 + i * 2048);
#pragma unroll
    for (int i = 0; i < 4; ++i) gload16(gB0 + ko + (size_t)i * 32 * HP, lB0 + i * 2048);
    __syncthreads();
#pragma unroll
    for (int s = 0; s < 2; ++s) {
      short8 av[4];
#pragma unroll
      for (int mi = 0; mi < 4; ++mi)
        av[mi] = *(const short8*)(sA + arow + mi * 16 * 64 + sw[s]);
#pragma unroll
      for (int ni = 0; ni < 4; ++ni) {
        short8 b8 = *(const short8*)(sB + brow + ni * 16 * 64 + sw[s]);
#pragma unroll
        for (int mi = 0; mi < 4; ++mi)
          acc[mi][ni] = __builtin_amdgcn_mfma_f32_16x16x32_bf16(av[mi], b8, acc[mi][ni], 0, 0, 0);
      }
    }
    __syncthreads();
  }

#pragma unroll
  for (int mi = 0; mi < 4; ++mi) {
#pragma unroll
    for (int rr = 0; rr < 4; ++rr) {
      int m_loc = wm * 64 + mi * 16 + q * 4 + rr;
      int m = m0 + m_loc;
      if (m >= Me) continue;
      size_t orow = (size_t)(off + m) * E_DIM;
#pragma unroll
      for (int ni = 0; ni < 4; ++ni) {
        int n = n0 + wn * 64 + ni * 16 + r;
        pout[orow + n] = acc[mi][ni][rr] + bo[e * E_DIM + n];
      }
    }
  }
}

// ---------------- combine + residual + LayerNorm ----------------
__global__ __launch_bounds__(256) void ln_k(const float* __restrict__ x,
    const float* __restrict__ pout, const int* __restrict__ pair_pos,
    const float* __restrict__ pair_w, const float* __restrict__ ln_g,
    const float* __restrict__ ln_b, float* __restrict__ out) {
  int t = blockIdx.x, tid = threadIdx.x;
  int p0 = pair_pos[2 * t], p1 = pair_pos[2 * t + 1];
  float w0 = pair_w[p0], w1 = pair_w[p1];
  const float* xr = x + (size_t)t * E_DIM;
  const float* r0 = pout + (size_t)p0 * E_DIM;
  const float* r1 = pout + (size_t)p1 * E_DIM;
  float y[4];
  float s = 0.f, ss = 0.f;
#pragma unroll
  for (int i = 0; i < 4; ++i) {
    int e = tid + 256 * i;
    y[i] = xr[e] + w0 * r0[e] + w1 * r1[e];
    s += y[i];
    ss += y[i] * y[i];
  }
#pragma unroll
  for (int o = 32; o; o >>= 1) { s += __shfl_xor(s, o, 64); ss += __shfl_xor(ss, o, 64); }
  __shared__ float red[8];
  int wid = tid >> 6, lane = tid & 63;
  if (lane == 0) { red[wid] = s; red[4 + wid] = ss; }
  __syncthreads();
  s  = red[0] + red[1] + red[2] + red[3];
  ss = red[4] + red[5] + red[6] + red[7];
  float mu = s * (1.f / E_DIM);
  float var = ss * (1.f / E_DIM) - mu * mu;
  float rs = rsqrtf(var + LN_EPS);
#pragma unroll
  for (int i = 0; i < 4; ++i) {
    int e = tid + 256 * i;
    out[(size_t)t * E_DIM + e] = ln_g[e] * (y[i] - mu) * rs + ln_b[e];
  }
}

extern "C" void kernel_launch(void* const* d_in, const int* in_sizes, int n_in,
                              void* d_out, int out_size, void* d_ws, size_t ws_size,
                              hipStream_t stream) {
  const float* x    = (const float*)d_in[0];
  const float* Wr   = (const float*)d_in[1];
  const float* Wv   = (const float*)d_in[2];
  const float* bv   = (const float*)d_in[3];
  const float* Wg   = (const float*)d_in[4];
  const float* bg   = (const float*)d_in[5];
  const float* Wo   = (const float*)d_in[6];
  const float* bo   = (const float*)d_in[7];
  const float* ln_g = (const float*)d_in[8];
  const float* ln_b = (const float*)d_in[9];
  float* out = (float*)d_out;

  char* ws = (char*)d_ws;
  size_t off = 0;
  auto alloc = [&](size_t bytes) -> void* {
    void* p = ws + off;
    off = (off + bytes + 255) & ~(size_t)255;
    return p;
  };
  int*   counts     = (int*)alloc(32);
  int*   cursor     = (int*)alloc(32);
  int*   offsets    = (int*)alloc(32);
  int*   slot_e     = (int*)alloc(NSLOT * 4);
  int*   slot_m0    = (int*)alloc(NSLOT * 4);
  int*   tk_idx     = (int*)alloc((size_t)NTOK * 2 * 4);
  float* tk_w       = (float*)alloc((size_t)NTOK * 2 * 4);
  int*   pair_token = (int*)alloc((size_t)NPAIR * 4);
  float* pair_w     = (float*)alloc((size_t)NPAIR * 4);
  int*   pair_pos   = (int*)alloc((size_t)NPAIR * 4);
  __hip_bfloat16* xs   = (__hip_bfloat16*)alloc((size_t)(NPAIR + 128) * E_DIM * 2);
  __hip_bfloat16* hbuf = (__hip_bfloat16*)alloc((size_t)(NPAIR + 128) * HP * 2);
  float* pout = (float*)alloc((size_t)NPAIR * E_DIM * 4);

  size_t welems = (size_t)NEXP * HP * E_DIM;
  __hip_bfloat16* WvT = (__hip_bfloat16*)alloc(welems * 2);
  __hip_bfloat16* WgT = (__hip_bfloat16*)alloc(welems * 2);
  __hip_bfloat16* WoT = (__hip_bfloat16*)alloc(welems * 2);

  hipMemsetAsync(d_ws, 0, 1024, stream);  // counts / cursor / offsets / slots

  router_k<<<NTOK / 4, 256, 0, stream>>>(x, Wr, counts, tk_idx, tk_w);
  offsets_k<<<1, 64, 0, stream>>>(counts, offsets, cursor, slot_e, slot_m0);
  scatter_k<<<NTOK / 256, 256, 0, stream>>>(tk_idx, tk_w, cursor, pair_token, pair_w, pair_pos);
  gatherx_k<<<NPAIR, 256, 0, stream>>>(x, pair_token, xs);

  tcvt_k<<<dim3(HP / 64, E_DIM / 64, NEXP), 256, 0, stream>>>(
      Wv, WvT, E_DIM, HDIM, E_DIM, (size_t)E_DIM * HDIM, (size_t)HP * E_DIM);
  tcvt_k<<<dim3(HP / 64, E_DIM / 64, NEXP), 256, 0, stream>>>(
      Wg, WgT, E_DIM, HDIM, E_DIM, (size_t)E_DIM * HDIM, (size_t)HP * E_DIM);
  tcvt_k<<<dim3(E_DIM / 64, HP / 64, NEXP), 256, 0, stream>>>(
      Wo, WoT, HDIM, E_DIM, HP, (size_t)HDIM * E_DIM, (size_t)E_DIM * HP);

  gemm1_k<<<dim3(HP / 128, NSLOT), 256, 0, stream>>>(
      xs, counts, offsets, slot_e, slot_m0, bv, bg, WvT, WgT, hbuf);
  gemm2_k<<<dim3(E_DIM / 128, NSLOT), 256, 0, stream>>>(
      hbuf, counts, offsets, slot_e, slot_m0, bo, WoT, pout);

  ln_k<<<NTOK, 256, 0, stream>>>(x, pout, pair_pos, pair_w, ln_g, ln_b, out);
}